// Round 1
// baseline (548.995 us; speedup 1.0000x reference)
//
#include <hip/hip_runtime.h>
#include <math.h>

// Problem constants
#define N_CH   8192      // codebook dim (softmax axis)
#define N_PIX  8192      // b*h*w = 8*32*32
#define SCH    32        // n-superchunks in kernel 1
#define OUT_ZQ   0
#define OUT_DIFF 2097152
#define OUT_IND  2097153
#define LOG_N 9.010913348f   // ln(8192)

// K1: partial reductions over n for every pixel.
// grid (32 pixel-tiles of 256 px, 32 superchunks of 256 n); block 256 =
// 64 groups (4 consecutive pixels each -> float4 loads) x 4 subchunks (64 n each).
__global__ __launch_bounds__(256) void k1_partial(
    const float* __restrict__ z, const float* __restrict__ gn,
    float* __restrict__ wsM, int* __restrict__ wsI,
    float* __restrict__ wsZ, float* __restrict__ wsS)
{
    const int tile = blockIdx.x;          // 0..31
    const int sch  = blockIdx.y;          // 0..31
    const int t    = threadIdx.x;
    const int grp  = t & 63;
    const int sub  = t >> 6;

    const int p0 = tile * 256 + grp * 4;  // first of 4 consecutive pixels
    const int b  = p0 >> 10;
    const int q0 = p0 & 1023;             // h*32+w
    const int n0 = sch * 256 + sub * 64;
    const float* zp = z  + (size_t)b * (N_CH * 1024) + q0;
    const float* gp = gn + (size_t)b * (N_CH * 1024) + q0;

    float m0 = -INFINITY, m1 = -INFINITY, m2 = -INFINITY, m3 = -INFINITY;
    int   i0 = 0, i1 = 0, i2 = 0, i3 = 0;
    float za = 0.f, zb = 0.f, zc = 0.f, zd = 0.f;   // sum exp(z)
    float sa = 0.f, sb = 0.f, sc = 0.f, sd = 0.f;   // sum z*exp(z)

    #pragma unroll 4
    for (int j = 0; j < 64; ++j) {
        const int n = n0 + j;
        const float4 zv = *(const float4*)(zp + (size_t)n * 1024);
        const float4 gv = *(const float4*)(gp + (size_t)n * 1024);
        float l, e;
        l = zv.x + gv.x; if (l > m0) { m0 = l; i0 = n; }
        e = __expf(zv.x); za += e; sa = fmaf(e, zv.x, sa);
        l = zv.y + gv.y; if (l > m1) { m1 = l; i1 = n; }
        e = __expf(zv.y); zb += e; sb = fmaf(e, zv.y, sb);
        l = zv.z + gv.z; if (l > m2) { m2 = l; i2 = n; }
        e = __expf(zv.z); zc += e; sc = fmaf(e, zv.z, sc);
        l = zv.w + gv.w; if (l > m3) { m3 = l; i3 = n; }
        e = __expf(zv.w); zd += e; sd = fmaf(e, zv.w, sd);
    }

    // combine 4 subchunks per pixel via LDS (once per kernel; conflicts irrelevant)
    __shared__ float lm[4][256];
    __shared__ int   li[4][256];
    __shared__ float lz[4][256];
    __shared__ float ls[4][256];
    const int pl = grp * 4;
    lm[sub][pl+0] = m0; lm[sub][pl+1] = m1; lm[sub][pl+2] = m2; lm[sub][pl+3] = m3;
    li[sub][pl+0] = i0; li[sub][pl+1] = i1; li[sub][pl+2] = i2; li[sub][pl+3] = i3;
    lz[sub][pl+0] = za; lz[sub][pl+1] = zb; lz[sub][pl+2] = zc; lz[sub][pl+3] = zd;
    ls[sub][pl+0] = sa; ls[sub][pl+1] = sb; ls[sub][pl+2] = sc; ls[sub][pl+3] = sd;
    __syncthreads();

    // ascending-sub order + strict '>' preserves numpy first-argmax semantics
    float M = -INFINITY; int I = 0; float Z = 0.f, S = 0.f;
    #pragma unroll
    for (int s = 0; s < 4; ++s) {
        const float mm = lm[s][t];
        if (mm > M) { M = mm; I = li[s][t]; }
        Z += lz[s][t];
        S += ls[s][t];
    }
    const int p = tile * 256 + t;
    wsM[sch * N_PIX + p] = M;
    wsI[sch * N_PIX + p] = I;
    wsZ[sch * N_PIX + p] = Z;
    wsS[sch * N_PIX + p] = S;
}

// K2: combine the 32 superchunk partials per pixel; emit ind + per-block KL sum.
__global__ __launch_bounds__(256) void k2_final(
    const float* __restrict__ wsM, const int* __restrict__ wsI,
    const float* __restrict__ wsZ, const float* __restrict__ wsS,
    float* __restrict__ out, int* __restrict__ wsInd, float* __restrict__ wsKl)
{
    const int p = blockIdx.x * 256 + threadIdx.x;
    float M = -INFINITY; int I = 0; float Z = 0.f, S = 0.f;
    for (int s = 0; s < SCH; ++s) {
        const float mm = wsM[s * N_PIX + p];
        const int   ii = wsI[s * N_PIX + p];
        if (mm > M) { M = mm; I = ii; }
        Z += wsZ[s * N_PIX + p];
        S += wsS[s * N_PIX + p];
    }
    out[OUT_IND + p] = (float)I;   // whole d_out buffer is fp32; ind <= 8191 exact
    wsInd[p] = I;
    // sum_i qy_i*log(qy_i*n + eps) == S/Z - log(Z) + log(n)   (eps negligible)
    const float kl = S / Z - __logf(Z) + LOG_N;

    __shared__ float red[256];
    red[threadIdx.x] = kl;
    __syncthreads();
    for (int off = 128; off > 0; off >>= 1) {
        if (threadIdx.x < off) red[threadIdx.x] += red[threadIdx.x + off];
        __syncthreads();
    }
    if (threadIdx.x == 0) wsKl[blockIdx.x] = red[0];
}

// K3: 32 block-partials -> diff scalar
__global__ void k3_diff(const float* __restrict__ wsKl, float* __restrict__ out)
{
    float v = (threadIdx.x < 32) ? wsKl[threadIdx.x] : 0.f;
    #pragma unroll
    for (int off = 32; off > 0; off >>= 1) v += __shfl_down(v, off);
    if (threadIdx.x == 0) out[OUT_DIFF] = 5e-4f * (v * (1.0f / 8192.0f));
}

// K4: z_q[b,d,h,w] = embed[ind[b,h,w], d]  (y factor == 1.0 exactly within tol)
// One block per (b,h): stage 32 embed rows in LDS (stride 257 -> conflict-free),
// then coalesced writes over (d,w).
__global__ __launch_bounds__(256) void k4_zq(
    const float* __restrict__ emb, const int* __restrict__ indi,
    float* __restrict__ out)
{
    const int b = blockIdx.x >> 5;   // 0..7
    const int h = blockIdx.x & 31;   // 0..31
    const int t = threadIdx.x;

    __shared__ int   rows[32];
    __shared__ float tile[32 * 257];
    if (t < 32) rows[t] = indi[b * 1024 + h * 32 + t];
    __syncthreads();

    for (int j = 0; j < 32; ++j) {
        const int r = rows[j];
        tile[j * 257 + t] = emb[r * 256 + t];   // coalesced 1 KiB per iter
    }
    __syncthreads();

    const int w  = t & 31;
    const int dg = t >> 5;           // 0..7
    const int obase = b * (256 * 1024) + h * 32 + w;
    #pragma unroll 4
    for (int k = 0; k < 32; ++k) {
        const int d = dg + k * 8;
        out[obase + d * 1024] = tile[w * 257 + d];  // banks (w+d)%32: conflict-free
    }
}

extern "C" void kernel_launch(void* const* d_in, const int* in_sizes, int n_in,
                              void* d_out, int out_size, void* d_ws, size_t ws_size,
                              hipStream_t stream)
{
    const float* z   = (const float*)d_in[0];   // (8, 8192, 32, 32)
    const float* emb = (const float*)d_in[1];   // (8192, 256)
    const float* gn  = (const float*)d_in[2];   // (8, 8192, 32, 32)
    float* out = (float*)d_out;

    char* ws = (char*)d_ws;                     // ~4.3 MiB used
    float* wsM   = (float*)(ws);                         // 1 MiB
    int*   wsI   = (int*)  (ws + (1u << 20));            // 1 MiB
    float* wsZ   = (float*)(ws + (2u << 20));            // 1 MiB
    float* wsS   = (float*)(ws + (3u << 20));            // 1 MiB
    int*   wsInd = (int*)  (ws + (4u << 20));            // 32 KiB
    float* wsKl  = (float*)(ws + (4u << 20) + 65536);    // 128 B

    k1_partial<<<dim3(32, 32), 256, 0, stream>>>(z, gn, wsM, wsI, wsZ, wsS);
    k2_final  <<<32, 256, 0, stream>>>(wsM, wsI, wsZ, wsS, out, wsInd, wsKl);
    k3_diff   <<<1, 64, 0, stream>>>(wsKl, out);
    k4_zq     <<<256, 256, 0, stream>>>(emb, wsInd, out);
}